// Round 5
// baseline (16114.688 us; speedup 1.0000x reference)
//
#include <hip/hip_runtime.h>
#include <hip/hip_bf16.h>
#include <stdint.h>

typedef unsigned int u32;
typedef unsigned long long u64;
typedef __attribute__((ext_vector_type(8))) short short8;
typedef __attribute__((ext_vector_type(4))) float floatx4;

#define T_STEPS 4096
#define BATCH   15
#define N_IN    512
#define N_H     1024
#define G_LAUNCH 64          // launched scan WGs; 8 elected (one XCD) participate
#define THREADS 512
#define LDS_ROW 516          // u32 per h row: 512 + 4 pad

// ---------- ws layout (bytes) ----------
#define OFF_XP    0
#define OFF_WIHB  (134217728)
#define OFF_HBUF  (134217728 + 1048576)           // u32[2][16][512] = 64 KB (row 15 = zero pad)
#define OFF_FLAGS (134217728 + 1048576 + 65536)   // u64[8] @ 64B spacing = 512 B
#define OFF_CLAIM (134217728 + 1048576 + 65536 + 512)  // u32[16]: 8 counters + winner

__device__ inline u32 f2bf1(float f) {            // fp32 -> bf16 (RNE), as u32
    u32 u = __builtin_bit_cast(u32, f);
    return (u + 0x7FFFu + ((u >> 16) & 1u)) >> 16;
}
__device__ inline float bf2f(u32 us) {            // bf16 (low 16) -> fp32
    return __builtin_bit_cast(float, us << 16);
}
__device__ inline float tanh_fast(float x) {
    float e = __expf(2.0f * x);                   // inf-safe at both ends
    return 1.0f - 2.0f / (e + 1.0f);
}
// Agent-scope load: bypasses L1, hits the shared same-XCD L2 (proven: exchange
// runs with ~zero EA traffic). Used for flag polls AND data reads.
__device__ inline u64 mb_load(const u64* p) {
    return __hip_atomic_load(p, __ATOMIC_RELAXED, __HIP_MEMORY_SCOPE_AGENT);
}
// Publish store: plain/workgroup scope — dirty line in the local XCD L2.
__device__ inline void pub_store32(u32* p, u32 v) {
    __hip_atomic_store(p, v, __ATOMIC_RELAXED, __HIP_MEMORY_SCOPE_WORKGROUP);
}
// Release fence: force all outstanding vmem acked (stores committed in L2).
// The xp prefetch is issued at the TOP of the step so it has ~1000cy to
// complete before this wait — R4 issued it ~150cy before the fence and ate
// an HBM-latency stall inside the producer->flag critical path every step.
__device__ inline void release_fence() {
    asm volatile("s_waitcnt vmcnt(0)" ::: "memory");
}

// ---------------- kernel 0: convert W_ih to packed bf16 (+ init claim/flags/zero-row) ----------------
__global__ void k_cvt_wih(const float* __restrict__ W_ih, u32* __restrict__ wihb,
                          u32* __restrict__ claim, u32* __restrict__ hbuf,
                          u64* __restrict__ fl) {
    int row = blockIdx.x;
    int tid = threadIdx.x;
    if (row == 0 && tid < 16) claim[tid] = 0;
    // flags: zero via agent-scope atomics (land at the coherence point, so a
    // fresh-launch L2 fetch can never observe pre-init garbage).
    if (row == 0 && tid >= 16 && tid < 24)
        __hip_atomic_exchange(fl + (size_t)(tid - 16) * 8, 0ull,
                              __ATOMIC_RELAXED, __HIP_MEMORY_SCOPE_AGENT);
    // hbuf batch-row 15 (both parities) must read as zero forever.
    if ((row == 1 || row == 2) && tid < 256) {
        u64* hz = (u64*)(hbuf + ((size_t)(row - 1) * 16 + 15) * 512);
        __hip_atomic_exchange(hz + tid, 0ull,
                              __ATOMIC_RELAXED, __HIP_MEMORY_SCOPE_AGENT);
    }
    const float* p = W_ih + (size_t)row * N_IN + tid * 2;
    u32 packed = f2bf1(p[0]) | (f2bf1(p[1]) << 16);
    wihb[row * (N_IN / 2) + tid] = packed;
}

// ---------------- kernel 1: x_proj GEMM ----------------
// xp[((t*64 + cw)*64 + lane)] = bf16x4 (rows quad*4+i, col cw*16+(l&15))
__global__ void __launch_bounds__(256) k_xproj(
        const float* __restrict__ x, const u32* __restrict__ wihb,
        const float* __restrict__ b_ih, const float* __restrict__ b_hh,
        u64* __restrict__ xp) {
    const int t     = blockIdx.x;
    const int slice = blockIdx.y;
    const int tid   = threadIdx.x;
    const int wave  = tid >> 6;
    const int l     = tid & 63;
    const int row   = l & 15;       // batch
    const int quad  = l >> 4;
    const int colbase = slice * 256 + wave * 64;

    floatx4 acc[4] = {{0,0,0,0},{0,0,0,0},{0,0,0,0},{0,0,0,0}};
    const float* xrow = x + ((size_t)row * T_STEPS + t) * N_IN;

    #pragma unroll
    for (int kk = 0; kk < 16; ++kk) {
        short8 a;
        if (row < 15) {
            const float* pa = xrow + kk * 32 + quad * 8;
            float4 x0 = *(const float4*)(pa);
            float4 x1 = *(const float4*)(pa + 4);
            a[0]=(short)f2bf1(x0.x); a[1]=(short)f2bf1(x0.y); a[2]=(short)f2bf1(x0.z); a[3]=(short)f2bf1(x0.w);
            a[4]=(short)f2bf1(x1.x); a[5]=(short)f2bf1(x1.y); a[6]=(short)f2bf1(x1.z); a[7]=(short)f2bf1(x1.w);
        } else {
            #pragma unroll
            for (int j = 0; j < 8; ++j) a[j] = 0;
        }
        #pragma unroll
        for (int c4 = 0; c4 < 4; ++c4) {
            int col = colbase + c4 * 16 + (l & 15);
            const uint4* pb = (const uint4*)(wihb + (size_t)col * (N_IN/2) + kk * 16 + quad * 4);
            short8 b = __builtin_bit_cast(short8, *pb);
            acc[c4] = __builtin_amdgcn_mfma_f32_16x16x32_bf16(a, b, acc[c4], 0, 0, 0);
        }
    }
    #pragma unroll
    for (int c4 = 0; c4 < 4; ++c4) {
        int col = colbase + c4 * 16 + (l & 15);
        float bias = b_ih[col] + b_hh[col];
        u64 packed = (u64)f2bf1(acc[c4][0] + bias)
                   | ((u64)f2bf1(acc[c4][1] + bias) << 16)
                   | ((u64)f2bf1(acc[c4][2] + bias) << 32)
                   | ((u64)f2bf1(acc[c4][3] + bias) << 48);
        int cw = slice * 16 + wave * 4 + c4;
        xp[((size_t)t * 64 + cw) * 64 + l] = packed;
    }
}

// ---------------- kernel 2: sequential scan (8 elected WGs on ONE XCD) ----------------
__global__ void __launch_bounds__(THREADS, 2) k_scan(
        const float* __restrict__ W_hh, const u64* __restrict__ xp,
        u32* __restrict__ hbuf, u64* __restrict__ fl, u32* __restrict__ claim,
        const float* __restrict__ W_fc, const float* __restrict__ b_fc,
        float* __restrict__ out) {
    __shared__ u32 h_lds[2][16 * LDS_ROW];   // ping-pong h (bf16 pairs), row 15 = zero pad
    __shared__ float red[256];
    __shared__ int s_slot;
    __shared__ int s_dead;

    const int tid  = threadIdx.x;      // 0..511
    const int wave = tid >> 6;
    const int l    = tid & 63;
    const int c    = l & 15;           // col-in-tile (B/C role) == batch (A role)
    const int quad = l >> 4;

    // ---- XCD election: 8 co-XCD WGs win; others exit ----
    if (tid == 0) {
        u32 xcd;
        asm volatile("s_getreg_b32 %0, hwreg(HW_REG_XCC_ID)" : "=s"(xcd));
        xcd &= 7u;
        u32 slot = __hip_atomic_fetch_add(&claim[xcd], 1u, __ATOMIC_RELAXED,
                                          __HIP_MEMORY_SCOPE_AGENT);
        if (slot == 7u) {
            u32 exp = 0u;
            __hip_atomic_compare_exchange_strong(&claim[8], &exp, xcd + 1u,
                __ATOMIC_RELAXED, __ATOMIC_RELAXED, __HIP_MEMORY_SCOPE_AGENT);
        }
        u32 w = 0; int gg = 0;
        do { w = __hip_atomic_load(&claim[8], __ATOMIC_RELAXED, __HIP_MEMORY_SCOPE_AGENT); }
        while (!w && ++gg < (1 << 22));
        s_slot = (w == xcd + 1u && slot < 8u) ? (int)slot : -1;
        s_dead = 0;
    }
    __syncthreads();
    const int g = s_slot;              // 0..7 for participants
    if (g < 0) return;

    const int col  = g * 128 + wave * 16 + c;
    const int cw   = g * 8 + wave;
    u64* myfl = fl + (size_t)g * 8;

    // LDS staging ownership: row = tid&15, block = tid>>4.  Memory layout is
    // IDENTICAL to linear (readers untouched); only thread ownership changes.
    // Bank = 4*(tid&15) + 16*((tid>>4)&1): 4-way max on ds_write_b64 (R4's
    // (tid>>5,tid&31) mapping was 16-way: all block starts on banks {0,16}).
    const int fr = tid & 15;           // staging row (batch)
    const int fb = tid >> 4;           // staging 16-u32 block (0..31)

    // --- W_hh fragments permanently in registers ---
    short8 wf[32];
    {
        const float* wr = W_hh + (size_t)col * N_H;
        #pragma unroll
        for (int kk = 0; kk < 32; ++kk) {
            const float* p = wr + kk * 32 + quad * 8;
            float4 w0 = *(const float4*)(p);
            float4 w1 = *(const float4*)(p + 4);
            short8 bfr;
            bfr[0]=(short)f2bf1(w0.x); bfr[1]=(short)f2bf1(w0.y); bfr[2]=(short)f2bf1(w0.z); bfr[3]=(short)f2bf1(w0.w);
            bfr[4]=(short)f2bf1(w1.x); bfr[5]=(short)f2bf1(w1.y); bfr[6]=(short)f2bf1(w1.z); bfr[7]=(short)f2bf1(w1.w);
            wf[kk] = bfr;
        }
    }
    for (int i = tid; i < 2 * 16 * LDS_ROW; i += THREADS) ((u32*)h_lds)[i] = 0;
    __syncthreads();

    // ---- step 0: h(1) = tanh(xp(0)); publish parity 1; flag = 1 ----
    u64 xpw = xp[((size_t)0 * 64 + cw) * 64 + l];
    u64 xpw_n = xp[((size_t)1 * 64 + cw) * 64 + l];   // prefetch BEFORE the fence region
    float h[4];
    {
        h[0] = tanh_fast(bf2f((u32)(xpw      ) & 0xFFFFu));
        h[1] = tanh_fast(bf2f((u32)(xpw >> 16) & 0xFFFFu));
        h[2] = tanh_fast(bf2f((u32)(xpw >> 32) & 0xFFFFu));
        h[3] = tanh_fast(bf2f((u32)(xpw >> 48) & 0xFFFFu));
        u32* bufw = hbuf + (size_t)1 * (16 * 512);
        #pragma unroll
        for (int i = 0; i < 4; ++i) {
            int bt = quad * 4 + i;
            float o = __shfl_xor(h[i], 1);
            if (!(c & 1) && bt < 15) {
                u32 data = f2bf1(h[i]) | (f2bf1(o) << 16);
                pub_store32(bufw + bt * 512 + (col >> 1), data);
            }
        }
        release_fence();               // data committed in L2 ...
        __syncthreads();               // ... by ALL threads ...
        if (tid == 0)                  // ... before the flag goes up
            __hip_atomic_store(myfl, 1ull, __ATOMIC_RELAXED, __HIP_MEMORY_SCOPE_WORKGROUP);
    }

    for (int s = 1; s < T_STEPS; ++s) {
        xpw = xpw_n;
        const int par = s & 1;
        u32* lds = &h_lds[par][0];

        // ---- xp prefetch for step s+1: issued at the TOP of the step so the
        // HBM latency hides under poll+fetch+MFMA, not under the fence ----
        if (s + 1 < T_STEPS) xpw_n = xp[((size_t)(s + 1) * 64 + cw) * 64 + l];

        // ---- wait: poll the 8 producer flags only (8B/thread/round) ----
        {
            const u64 want = (u64)s;
            int rounds = 0;
            while (true) {
                u64 f = mb_load(fl + (size_t)(l & 7) * 8);
                if (__all((int)(f >= want))) break;
                if (++rounds > (1 << 20)) { s_dead = 1; break; }
            }
        }

        // ---- fetch h(s): 64B per thread, agent loads (L2 hits), into LDS ----
        {
            const u64* src = (const u64*)(hbuf + (size_t)par * (16 * 512))
                             + (size_t)fr * 256 + (size_t)fb * 8;
            u64 d0 = mb_load(src + 0), d1 = mb_load(src + 1);
            u64 d2 = mb_load(src + 2), d3 = mb_load(src + 3);
            u64 d4 = mb_load(src + 4), d5 = mb_load(src + 5);
            u64 d6 = mb_load(src + 6), d7 = mb_load(src + 7);
            u64* dst = (u64*)(lds + (size_t)fr * LDS_ROW + (size_t)fb * 16);
            dst[0] = d0; dst[1] = d1; dst[2] = d2; dst[3] = d3;
            dst[4] = d4; dst[5] = d5; dst[6] = d6; dst[7] = d7;
        }
        __syncthreads();
        if (s_dead) break;

        // ---- compute: fully-unrolled dual-accumulator MFMA chain ----
        floatx4 acc0, acc1;
        acc0[0] = bf2f((u32)(xpw      ) & 0xFFFFu);
        acc0[1] = bf2f((u32)(xpw >> 16) & 0xFFFFu);
        acc0[2] = bf2f((u32)(xpw >> 32) & 0xFFFFu);
        acc0[3] = bf2f((u32)(xpw >> 48) & 0xFFFFu);
        acc1[0] = 0.f; acc1[1] = 0.f; acc1[2] = 0.f; acc1[3] = 0.f;

        #pragma unroll
        for (int t = 0; t < 16; ++t) {
            uint4 a0 = *(const uint4*)&lds[c * LDS_ROW + (2 * t    ) * 16 + quad * 4];
            uint4 a1 = *(const uint4*)&lds[c * LDS_ROW + (2 * t + 1) * 16 + quad * 4];
            acc0 = __builtin_amdgcn_mfma_f32_16x16x32_bf16(
                       __builtin_bit_cast(short8, a0), wf[2 * t    ], acc0, 0, 0, 0);
            acc1 = __builtin_amdgcn_mfma_f32_16x16x32_bf16(
                       __builtin_bit_cast(short8, a1), wf[2 * t + 1], acc1, 0, 0, 0);
        }

        #pragma unroll
        for (int i = 0; i < 4; ++i) h[i] = tanh_fast(acc0[i] + acc1[i]);

        // ---- publish h(s+1) -> parity (s+1)&1; fence; barrier; flag = s+1 ----
        u32* bufw = hbuf + (size_t)((s + 1) & 1) * (16 * 512);
        #pragma unroll
        for (int i = 0; i < 4; ++i) {
            int bt = quad * 4 + i;
            float o = __shfl_xor(h[i], 1);
            if (!(c & 1) && bt < 15) {
                u32 data = f2bf1(h[i]) | (f2bf1(o) << 16);
                pub_store32(bufw + bt * 512 + (col >> 1), data);
            }
        }
        release_fence();
        __syncthreads();
        if (tid == 0)
            __hip_atomic_store(myfl, (u64)(s + 1), __ATOMIC_RELAXED, __HIP_MEMORY_SCOPE_WORKGROUP);
    }

    // ---------------- epilogue: elected WG 0 computes the sigmoid head ----------------
    if (g == 0) {
        if (!s_dead) {
            const u64 want = (u64)T_STEPS;
            int rounds = 0;
            while (true) {
                u64 f = mb_load(fl + (size_t)(l & 7) * 8);
                if (__all((int)(f >= want))) break;
                if (++rounds > (1 << 20)) break;
            }
            u32* lds = &h_lds[0][0];
            const u64* src = (const u64*)(hbuf + (size_t)0)
                             + (size_t)fr * 256 + (size_t)fb * 8;   // parity 0
            u64 d0 = mb_load(src + 0), d1 = mb_load(src + 1);
            u64 d2 = mb_load(src + 2), d3 = mb_load(src + 3);
            u64 d4 = mb_load(src + 4), d5 = mb_load(src + 5);
            u64 d6 = mb_load(src + 6), d7 = mb_load(src + 7);
            u64* dst = (u64*)(lds + (size_t)fr * LDS_ROW + (size_t)fb * 16);
            dst[0] = d0; dst[1] = d1; dst[2] = d2; dst[3] = d3;
            dst[4] = d4; dst[5] = d5; dst[6] = d6; dst[7] = d7;
        }
        __syncthreads();
        u32* lds = &h_lds[0][0];
        if (tid < 240) {
            int b = tid >> 4, seg = tid & 15;
            float sum = 0.f;
            for (int j = 0; j < 64; ++j) {
                int k = seg * 64 + j;
                u32 pr = lds[b * LDS_ROW + (k >> 1)];
                float hv = bf2f((pr >> ((k & 1) * 16)) & 0xFFFFu);
                sum += hv * W_fc[k];
            }
            red[tid] = sum;
        }
        __syncthreads();
        if (tid < 15) {
            float z = 0.f;
            #pragma unroll
            for (int j = 0; j < 16; ++j) z += red[tid * 16 + j];
            z += b_fc[0];
            out[tid] = 1.0f / (1.0f + __expf(-z));
        }
    }
}

extern "C" void kernel_launch(void* const* d_in, const int* in_sizes, int n_in,
                              void* d_out, int out_size, void* d_ws, size_t ws_size,
                              hipStream_t stream) {
    const float* x    = (const float*)d_in[0];
    const float* W_ih = (const float*)d_in[1];
    const float* b_ih = (const float*)d_in[2];
    const float* W_hh = (const float*)d_in[3];
    const float* b_hh = (const float*)d_in[4];
    const float* W_fc = (const float*)d_in[5];
    const float* b_fc = (const float*)d_in[6];
    float* out = (float*)d_out;

    char* ws    = (char*)d_ws;
    u64*  xp    = (u64*)(ws + OFF_XP);
    u32*  wihb  = (u32*)(ws + OFF_WIHB);
    u32*  hbuf  = (u32*)(ws + OFF_HBUF);
    u64*  fl    = (u64*)(ws + OFF_FLAGS);
    u32*  claim = (u32*)(ws + OFF_CLAIM);

    k_cvt_wih<<<dim3(N_H), dim3(256), 0, stream>>>(W_ih, wihb, claim, hbuf, fl);
    k_xproj<<<dim3(T_STEPS, 4), dim3(256), 0, stream>>>(x, wihb, b_ih, b_hh, xp);
    k_scan<<<dim3(G_LAUNCH), dim3(THREADS), 0, stream>>>(W_hh, xp, hbuf, fl, claim, W_fc, b_fc, out);
}

// Round 6
// 11672.303 us; speedup vs baseline: 1.3806x; 1.3806x over previous
//
#include <hip/hip_runtime.h>
#include <hip/hip_bf16.h>
#include <stdint.h>

typedef unsigned int u32;
typedef unsigned long long u64;
typedef __attribute__((ext_vector_type(8))) short short8;
typedef __attribute__((ext_vector_type(4))) float floatx4;

#define T_STEPS 4096
#define BATCH   15
#define N_IN    512
#define N_H     1024
#define G_LAUNCH 64          // launched scan WGs; 8 elected (one XCD) participate
#define THREADS 512
#define LDS_ROW 516          // u32 per h row: 512 + 4 pad

// ---------- ws layout (bytes) ----------
#define OFF_XP    0
#define OFF_WIHB  (134217728)
#define OFF_HBUF  (134217728 + 1048576)           // u32[2][16][512] = 64 KB (row 15 = zero pad)
#define OFF_FLAGS (134217728 + 1048576 + 65536)   // u64[64] @ 64B spacing = 4 KB (per-wave flags)
#define OFF_CLAIM (134217728 + 1048576 + 65536 + 4096)  // u32[16]: 8 counters + winner

__device__ inline u32 f2bf1(float f) {            // fp32 -> bf16 (RNE), as u32
    u32 u = __builtin_bit_cast(u32, f);
    return (u + 0x7FFFu + ((u >> 16) & 1u)) >> 16;
}
__device__ inline float bf2f(u32 us) {            // bf16 (low 16) -> fp32
    return __builtin_bit_cast(float, us << 16);
}
__device__ inline float tanh_fast(float x) {
    float e = __expf(2.0f * x);                   // inf-safe at both ends
    return 1.0f - 2.0f / (e + 1.0f);
}
// Agent-scope load: bypasses L1, hits the shared same-XCD L2 (proven: exchange
// runs with ~zero EA traffic). Used for flag polls AND data reads.
__device__ inline u64 mb_load(const u64* p) {
    return __hip_atomic_load(p, __ATOMIC_RELAXED, __HIP_MEMORY_SCOPE_AGENT);
}
// Publish store: plain/workgroup scope — dirty line in the local XCD L2.
__device__ inline void pub_store32(u32* p, u32 v) {
    __hip_atomic_store(p, v, __ATOMIC_RELAXED, __HIP_MEMORY_SCOPE_WORKGROUP);
}
__device__ inline void pub_store64(u64* p, u64 v) {
    __hip_atomic_store(p, v, __ATOMIC_RELAXED, __HIP_MEMORY_SCOPE_WORKGROUP);
}
// Per-wave release fence: vmcnt is per-wave, so this waits only THIS wave's
// publish stores (acked by L2). The xp prefetch is consumed (asm use) before
// this point, so the fence never eats HBM latency.
__device__ inline void release_fence() {
    asm volatile("s_waitcnt vmcnt(0)" ::: "memory");
}

// ---------------- kernel 0: convert W_ih to packed bf16 (+ init claim/flags/zero-row) ----------------
__global__ void k_cvt_wih(const float* __restrict__ W_ih, u32* __restrict__ wihb,
                          u32* __restrict__ claim, u32* __restrict__ hbuf,
                          u64* __restrict__ fl) {
    int row = blockIdx.x;
    int tid = threadIdx.x;
    if (row == 0 && tid < 16) claim[tid] = 0;
    // 64 per-wave flags: zero via agent-scope atomics (coherence point).
    if (row == 0 && tid >= 16 && tid < 80)
        __hip_atomic_exchange(fl + (size_t)(tid - 16) * 8, 0ull,
                              __ATOMIC_RELAXED, __HIP_MEMORY_SCOPE_AGENT);
    // hbuf batch-row 15 (both parities) must read as zero forever.
    if ((row == 1 || row == 2) && tid < 256) {
        u64* hz = (u64*)(hbuf + ((size_t)(row - 1) * 16 + 15) * 512);
        __hip_atomic_exchange(hz + tid, 0ull,
                              __ATOMIC_RELAXED, __HIP_MEMORY_SCOPE_AGENT);
    }
    const float* p = W_ih + (size_t)row * N_IN + tid * 2;
    u32 packed = f2bf1(p[0]) | (f2bf1(p[1]) << 16);
    wihb[row * (N_IN / 2) + tid] = packed;
}

// ---------------- kernel 1: x_proj GEMM ----------------
// xp[((t*64 + cw)*64 + lane)] = bf16x4 (rows quad*4+i, col cw*16+(l&15))
__global__ void __launch_bounds__(256) k_xproj(
        const float* __restrict__ x, const u32* __restrict__ wihb,
        const float* __restrict__ b_ih, const float* __restrict__ b_hh,
        u64* __restrict__ xp) {
    const int t     = blockIdx.x;
    const int slice = blockIdx.y;
    const int tid   = threadIdx.x;
    const int wave  = tid >> 6;
    const int l     = tid & 63;
    const int row   = l & 15;       // batch
    const int quad  = l >> 4;
    const int colbase = slice * 256 + wave * 64;

    floatx4 acc[4] = {{0,0,0,0},{0,0,0,0},{0,0,0,0},{0,0,0,0}};
    const float* xrow = x + ((size_t)row * T_STEPS + t) * N_IN;

    #pragma unroll
    for (int kk = 0; kk < 16; ++kk) {
        short8 a;
        if (row < 15) {
            const float* pa = xrow + kk * 32 + quad * 8;
            float4 x0 = *(const float4*)(pa);
            float4 x1 = *(const float4*)(pa + 4);
            a[0]=(short)f2bf1(x0.x); a[1]=(short)f2bf1(x0.y); a[2]=(short)f2bf1(x0.z); a[3]=(short)f2bf1(x0.w);
            a[4]=(short)f2bf1(x1.x); a[5]=(short)f2bf1(x1.y); a[6]=(short)f2bf1(x1.z); a[7]=(short)f2bf1(x1.w);
        } else {
            #pragma unroll
            for (int j = 0; j < 8; ++j) a[j] = 0;
        }
        #pragma unroll
        for (int c4 = 0; c4 < 4; ++c4) {
            int col = colbase + c4 * 16 + (l & 15);
            const uint4* pb = (const uint4*)(wihb + (size_t)col * (N_IN/2) + kk * 16 + quad * 4);
            short8 b = __builtin_bit_cast(short8, *pb);
            acc[c4] = __builtin_amdgcn_mfma_f32_16x16x32_bf16(a, b, acc[c4], 0, 0, 0);
        }
    }
    #pragma unroll
    for (int c4 = 0; c4 < 4; ++c4) {
        int col = colbase + c4 * 16 + (l & 15);
        float bias = b_ih[col] + b_hh[col];
        u64 packed = (u64)f2bf1(acc[c4][0] + bias)
                   | ((u64)f2bf1(acc[c4][1] + bias) << 16)
                   | ((u64)f2bf1(acc[c4][2] + bias) << 32)
                   | ((u64)f2bf1(acc[c4][3] + bias) << 48);
        int cw = slice * 16 + wave * 4 + c4;
        xp[((size_t)t * 64 + cw) * 64 + l] = packed;
    }
}

// ---------------- kernel 2: sequential scan (8 elected WGs on ONE XCD) ----------------
__global__ void __launch_bounds__(THREADS, 2) k_scan(
        const float* __restrict__ W_hh, const u64* __restrict__ xp,
        u32* __restrict__ hbuf, u64* __restrict__ fl, u32* __restrict__ claim,
        const float* __restrict__ W_fc, const float* __restrict__ b_fc,
        float* __restrict__ out) {
    __shared__ u32 h_lds[2][16 * LDS_ROW];   // ping-pong h (bf16 pairs), row 15 = zero pad
    __shared__ float red[256];
    __shared__ int s_slot;
    __shared__ int s_dead;

    const int tid  = threadIdx.x;      // 0..511
    const int wave = tid >> 6;
    const int l    = tid & 63;
    const int c    = l & 15;           // col-in-tile (B/C role) == batch (A role)
    const int quad = l >> 4;

    // ---- XCD election: 8 co-XCD WGs win; others exit ----
    if (tid == 0) {
        u32 xcd;
        asm volatile("s_getreg_b32 %0, hwreg(HW_REG_XCC_ID)" : "=s"(xcd));
        xcd &= 7u;
        u32 slot = __hip_atomic_fetch_add(&claim[xcd], 1u, __ATOMIC_RELAXED,
                                          __HIP_MEMORY_SCOPE_AGENT);
        if (slot == 7u) {
            u32 exp = 0u;
            __hip_atomic_compare_exchange_strong(&claim[8], &exp, xcd + 1u,
                __ATOMIC_RELAXED, __ATOMIC_RELAXED, __HIP_MEMORY_SCOPE_AGENT);
        }
        u32 w = 0; int gg = 0;
        do { w = __hip_atomic_load(&claim[8], __ATOMIC_RELAXED, __HIP_MEMORY_SCOPE_AGENT); }
        while (!w && ++gg < (1 << 22));
        s_slot = (w == xcd + 1u && slot < 8u) ? (int)slot : -1;
        s_dead = 0;
    }
    __syncthreads();
    const int g = s_slot;              // 0..7 for participants
    if (g < 0) return;

    const int col  = g * 128 + wave * 16 + c;
    const int cw   = g * 8 + wave;
    const int wgf  = g * 8 + wave;     // global wave-flag index (0..63)

    // --- W_hh fragments permanently in registers ---
    short8 wf[32];
    {
        const float* wr = W_hh + (size_t)col * N_H;
        #pragma unroll
        for (int kk = 0; kk < 32; ++kk) {
            const float* p = wr + kk * 32 + quad * 8;
            float4 w0 = *(const float4*)(p);
            float4 w1 = *(const float4*)(p + 4);
            short8 bfr;
            bfr[0]=(short)f2bf1(w0.x); bfr[1]=(short)f2bf1(w0.y); bfr[2]=(short)f2bf1(w0.z); bfr[3]=(short)f2bf1(w0.w);
            bfr[4]=(short)f2bf1(w1.x); bfr[5]=(short)f2bf1(w1.y); bfr[6]=(short)f2bf1(w1.z); bfr[7]=(short)f2bf1(w1.w);
            wf[kk] = bfr;
        }
    }
    for (int i = tid; i < 2 * 16 * LDS_ROW; i += THREADS) ((u32*)h_lds)[i] = 0;
    __syncthreads();

    // ---- step 0: h(1) = tanh(xp(0)); publish parity 1; per-wave flag = 1 ----
    u64 xpw = xp[((size_t)0 * 64 + cw) * 64 + l];
    u64 xpw_n = xp[((size_t)1 * 64 + cw) * 64 + l];
    float h[4];
    {
        h[0] = tanh_fast(bf2f((u32)(xpw      ) & 0xFFFFu));
        h[1] = tanh_fast(bf2f((u32)(xpw >> 16) & 0xFFFFu));
        h[2] = tanh_fast(bf2f((u32)(xpw >> 32) & 0xFFFFu));
        h[3] = tanh_fast(bf2f((u32)(xpw >> 48) & 0xFFFFu));
        u32* bufw = hbuf + (size_t)1 * (16 * 512);
        #pragma unroll
        for (int i = 0; i < 4; ++i) {
            int bt = quad * 4 + i;
            float o = __shfl_xor(h[i], 1);
            if (!(c & 1) && bt < 15) {
                u32 data = f2bf1(h[i]) | (f2bf1(o) << 16);
                pub_store32(bufw + bt * 512 + (col >> 1), data);
            }
        }
        release_fence();               // this wave's data committed in L2
        if (l == 0) pub_store64(fl + (size_t)wgf * 8, 1ull);
    }

    for (int s = 1; s < T_STEPS; ++s) {
        xpw = xpw_n;
        const int par = s & 1;
        u32* lds = &h_lds[par][0];

        // ---- wait: poll the 64 per-wave flags (lane l owns flag l); nothing
        // else is outstanding in vmcnt, so each round is a clean L2 trip ----
        {
            const u64 want = (u64)s;
            int rounds = 0;
            while (true) {
                u64 f = mb_load(fl + (size_t)l * 8);
                if (__all((int)(f >= want))) break;
                if (++rounds > (1 << 20)) { s_dead = 1; break; }
            }
        }

        // ---- fetch h(s): COALESCED — inst k reads 512 consecutive bytes per
        // wave (8 L2 lines/inst vs 64 for the old tid*64B gather) ----
        {
            const u64* src = (const u64*)(hbuf + (size_t)par * (16 * 512));
            u64 d0 = mb_load(src + tid +    0), d1 = mb_load(src + tid +  512);
            u64 d2 = mb_load(src + tid + 1024), d3 = mb_load(src + tid + 1536);
            u64 d4 = mb_load(src + tid + 2048), d5 = mb_load(src + tid + 2560);
            u64 d6 = mb_load(src + tid + 3072), d7 = mb_load(src + tid + 3584);
            const int rbase = tid >> 8;          // 0 or 1
            const int cc    = (tid & 255) * 2;   // u32 col
            *(u64*)(lds + (size_t)(rbase +  0) * LDS_ROW + cc) = d0;
            *(u64*)(lds + (size_t)(rbase +  2) * LDS_ROW + cc) = d1;
            *(u64*)(lds + (size_t)(rbase +  4) * LDS_ROW + cc) = d2;
            *(u64*)(lds + (size_t)(rbase +  6) * LDS_ROW + cc) = d3;
            *(u64*)(lds + (size_t)(rbase +  8) * LDS_ROW + cc) = d4;
            *(u64*)(lds + (size_t)(rbase + 10) * LDS_ROW + cc) = d5;
            *(u64*)(lds + (size_t)(rbase + 12) * LDS_ROW + cc) = d6;
            *(u64*)(lds + (size_t)(rbase + 14) * LDS_ROW + cc) = d7;
        }
        __syncthreads();               // the ONLY barrier per step
        if (s_dead) break;

        // ---- xp prefetch for s+1: issued AFTER the barrier (never outstanding
        // during poll/fetch waits); consumed via asm-use after tanh so the
        // MFMA+tanh window covers its latency, not the fence ----
        if (s + 1 < T_STEPS) xpw_n = xp[((size_t)(s + 1) * 64 + cw) * 64 + l];

        // ---- compute: fully-unrolled dual-accumulator MFMA chain ----
        floatx4 acc0, acc1;
        acc0[0] = bf2f((u32)(xpw      ) & 0xFFFFu);
        acc0[1] = bf2f((u32)(xpw >> 16) & 0xFFFFu);
        acc0[2] = bf2f((u32)(xpw >> 32) & 0xFFFFu);
        acc0[3] = bf2f((u32)(xpw >> 48) & 0xFFFFu);
        acc1[0] = 0.f; acc1[1] = 0.f; acc1[2] = 0.f; acc1[3] = 0.f;

        #pragma unroll
        for (int t = 0; t < 16; ++t) {
            uint4 a0 = *(const uint4*)&lds[c * LDS_ROW + (2 * t    ) * 16 + quad * 4];
            uint4 a1 = *(const uint4*)&lds[c * LDS_ROW + (2 * t + 1) * 16 + quad * 4];
            acc0 = __builtin_amdgcn_mfma_f32_16x16x32_bf16(
                       __builtin_bit_cast(short8, a0), wf[2 * t    ], acc0, 0, 0, 0);
            acc1 = __builtin_amdgcn_mfma_f32_16x16x32_bf16(
                       __builtin_bit_cast(short8, a1), wf[2 * t + 1], acc1, 0, 0, 0);
        }

        #pragma unroll
        for (int i = 0; i < 4; ++i) h[i] = tanh_fast(acc0[i] + acc1[i]);

        // force the xp prefetch to complete HERE (covered by MFMA+tanh), so the
        // release fence below only waits for the 4 publish stores
        asm volatile("" :: "v"(xpw_n));

        // ---- publish h(s+1) -> parity (s+1)&1; per-wave fence; per-wave flag ----
        u32* bufw = hbuf + (size_t)((s + 1) & 1) * (16 * 512);
        #pragma unroll
        for (int i = 0; i < 4; ++i) {
            int bt = quad * 4 + i;
            float o = __shfl_xor(h[i], 1);
            if (!(c & 1) && bt < 15) {
                u32 data = f2bf1(h[i]) | (f2bf1(o) << 16);
                pub_store32(bufw + bt * 512 + (col >> 1), data);
            }
        }
        release_fence();
        if (l == 0) pub_store64(fl + (size_t)wgf * 8, (u64)(s + 1));
    }

    // ---------------- epilogue: elected WG 0 computes the sigmoid head ----------------
    if (g == 0) {
        if (!s_dead) {
            const u64 want = (u64)T_STEPS;
            int rounds = 0;
            while (true) {
                u64 f = mb_load(fl + (size_t)l * 8);
                if (__all((int)(f >= want))) break;
                if (++rounds > (1 << 20)) break;
            }
            u32* lds = &h_lds[0][0];
            const u64* src = (const u64*)(hbuf + (size_t)0);   // parity 0
            u64 d0 = mb_load(src + tid +    0), d1 = mb_load(src + tid +  512);
            u64 d2 = mb_load(src + tid + 1024), d3 = mb_load(src + tid + 1536);
            u64 d4 = mb_load(src + tid + 2048), d5 = mb_load(src + tid + 2560);
            u64 d6 = mb_load(src + tid + 3072), d7 = mb_load(src + tid + 3584);
            const int rbase = tid >> 8;
            const int cc    = (tid & 255) * 2;
            *(u64*)(lds + (size_t)(rbase +  0) * LDS_ROW + cc) = d0;
            *(u64*)(lds + (size_t)(rbase +  2) * LDS_ROW + cc) = d1;
            *(u64*)(lds + (size_t)(rbase +  4) * LDS_ROW + cc) = d2;
            *(u64*)(lds + (size_t)(rbase +  6) * LDS_ROW + cc) = d3;
            *(u64*)(lds + (size_t)(rbase +  8) * LDS_ROW + cc) = d4;
            *(u64*)(lds + (size_t)(rbase + 10) * LDS_ROW + cc) = d5;
            *(u64*)(lds + (size_t)(rbase + 12) * LDS_ROW + cc) = d6;
            *(u64*)(lds + (size_t)(rbase + 14) * LDS_ROW + cc) = d7;
        }
        __syncthreads();
        u32* lds = &h_lds[0][0];
        if (tid < 240) {
            int b = tid >> 4, seg = tid & 15;
            float sum = 0.f;
            for (int j = 0; j < 64; ++j) {
                int k = seg * 64 + j;
                u32 pr = lds[b * LDS_ROW + (k >> 1)];
                float hv = bf2f((pr >> ((k & 1) * 16)) & 0xFFFFu);
                sum += hv * W_fc[k];
            }
            red[tid] = sum;
        }
        __syncthreads();
        if (tid < 15) {
            float z = 0.f;
            #pragma unroll
            for (int j = 0; j < 16; ++j) z += red[tid * 16 + j];
            z += b_fc[0];
            out[tid] = 1.0f / (1.0f + __expf(-z));
        }
    }
}

extern "C" void kernel_launch(void* const* d_in, const int* in_sizes, int n_in,
                              void* d_out, int out_size, void* d_ws, size_t ws_size,
                              hipStream_t stream) {
    const float* x    = (const float*)d_in[0];
    const float* W_ih = (const float*)d_in[1];
    const float* b_ih = (const float*)d_in[2];
    const float* W_hh = (const float*)d_in[3];
    const float* b_hh = (const float*)d_in[4];
    const float* W_fc = (const float*)d_in[5];
    const float* b_fc = (const float*)d_in[6];
    float* out = (float*)d_out;

    char* ws    = (char*)d_ws;
    u64*  xp    = (u64*)(ws + OFF_XP);
    u32*  wihb  = (u32*)(ws + OFF_WIHB);
    u32*  hbuf  = (u32*)(ws + OFF_HBUF);
    u64*  fl    = (u64*)(ws + OFF_FLAGS);
    u32*  claim = (u32*)(ws + OFF_CLAIM);

    k_cvt_wih<<<dim3(N_H), dim3(256), 0, stream>>>(W_ih, wihb, claim, hbuf, fl);
    k_xproj<<<dim3(T_STEPS, 4), dim3(256), 0, stream>>>(x, wihb, b_ih, b_hh, xp);
    k_scan<<<dim3(G_LAUNCH), dim3(THREADS), 0, stream>>>(W_hh, xp, hbuf, fl, claim, W_fc, b_fc, out);
}